// Round 7
// baseline (292.529 us; speedup 1.0000x reference)
//
#include <hip/hip_runtime.h>
#include <cstdint>
#include <cstddef>

// ---------------------------------------------------------------------------
// SpatialGRU 32x32, B=64, U=64, C=64. R13 = R12 staircase + ONE change:
// the inter-group handoff stores are ATOMIC EXCHANGES (non-returning
// global_atomic_swap) instead of relaxed agent atomic stores. Theory: plain
// agent-scope atomic stores retire into the producer XCD's write-back L2 as
// dirty lines; the consumer's agent atomic load reads the MALL and sees
// stale data until eviction (µs-scale, traffic-dependent) — this is the
// fitted 15-25us per-hop latency that ate the staircase's structural win.
// Atomic RMWs execute AT the coherence point by construction and cannot
// linger in L2. If this lands 80-140us the theory is confirmed; if
// unchanged, L_f is small, c-limited confirmed -> attack barrier structure.
//
// R12 recap: 8 row-groups x 16 batch-tiles = 128 blocks, 4 rows/block
// staggered (cell k handles col s-k at step s), cells batch-fused into one
// M=16 GEMM pipeline; hT for cells 1..3 via LDS rotation (parity-buffered);
// only cell3 -> hbuf (128 dw/slot), only cell0 polls (128 threads).
// Serial path: 35 steps + 7 inter-block lags. 3 barriers/step.
// Validity: stored halfwords have LSB|=1; ws poison 0xAA fails the check.
// hbuf: (7 grp-edges, 32 cols, 16 bt) slots x 128 dwords = 1.83 MB.
// ---------------------------------------------------------------------------

#define LDIM   32
#define GRPS   8
#define RPB    4
#define NBT    16
#define BT     4
#define TPB    512
#define UNITS  64
#define STEPS  (LDIM + RPB - 1)   // 35

typedef _Float16 f16;
typedef _Float16 f16x8 __attribute__((ext_vector_type(8)));
typedef float    f32x4 __attribute__((ext_vector_type(4)));

__global__ __launch_bounds__(TPB, 2) void spatial_gru_kernel(
    const float* __restrict__ x,     // (B, C, 32, 32)
    const float* __restrict__ W,     // (256, 448)
    const float* __restrict__ Urec,  // (192, 64)
    const float* __restrict__ bias,  // (512,)
    const float* __restrict__ Wij,   // (64, 64)
    float* __restrict__ out,         // (B, U)
    uint32_t* __restrict__ hbuf)
{
    const int p   = blockIdx.x;
    const int grp = p >> 4;          // row group 0..7 (rows grp*4 .. grp*4+3)
    const int bt  = p & 15;          // batch tile 0..15 (batches bt*4..bt*4+3)
    const int t   = (int)threadIdx.x;
    const int u   = t & 63;
    const int g   = t >> 6;          // wave 0..7
    const int l15 = t & 15;          // MFMA A-row lane (M-row = cell*4+batch)
    const int lq  = (t & 63) >> 4;   // MFMA k-quad

    // ---- LDS ----
    // M-row m = cell*4 + batch_in_tile. All per-row, parity double-buffered.
    // qf  (f16): [m][ hT0 0 | hT1 64 | hL0 128 | hL1 192 | hD0 256 | hD1 320
    //               | x0 384 | x1 448 ]
    // qs32(f32): [m][ hT0 0 | hT1 64 | hL0 128 | hL1 192 | hD0 256 | hD1 320 ]
    // rf  (f16): [m][0:192] = r*{hL,hT,hD} (cur step, no parity needed)
    // Gsz (f32): [m][0:256] z logits
    __shared__ __attribute__((aligned(16))) f16 qf[16][520];
    __shared__ __attribute__((aligned(16))) f16 rf[16][200];
    __shared__ float qs32[16][388];
    __shared__ float Gsz [16][260];

    // ---- GEMM1 weights resident (waves 0..6: 64 n-cols each) ----
    f16x8 wreg[4][8];
    float bias1[4] = {0.f, 0.f, 0.f, 0.f};
    if (g < 7) {
        const int nb = g * 64 + l15;
#pragma unroll
        for (int T = 0; T < 4; ++T) {
            bias1[T] = bias[nb + 16 * T];
#pragma unroll
            for (int s = 0; s < 8; ++s) {
                f16x8 v;
#pragma unroll
                for (int jj = 0; jj < 8; ++jj) {
                    int kk = s * 32 + lq * 8 + jj;
                    v[jj] = (f16)W[(size_t)kk * 448 + nb + 16 * T];
                }
                wreg[T][s] = v;
            }
        }
    }
    // ---- GEMM2 weights: waves 4..7 hold FULL K=256 for 16 n-cols each ----
    f16x8 wreg2[8];
    float bijE = 0.f;
    if (g >= 4) {
        const int nn = (g - 4) * 16 + l15;
        bijE = bias[448 + nn];
#pragma unroll
        for (int s = 0; s < 8; ++s) {
            f16x8 v;
#pragma unroll
            for (int jj = 0; jj < 8; ++jj) {
                int kk = s * 32 + lq * 8 + jj;
                float wv = (kk < 192) ? Urec[kk * 64 + nn] : Wij[(kk - 192) * 64 + nn];
                v[jj] = (f16)wv;
            }
            wreg2[s] = v;
        }
    }

    // ---- zero init all states (both parities) ----
    for (int idx = t; idx < 16 * 388; idx += TPB) {
        int b = idx & 15, k = idx >> 4;
        qs32[b][k] = 0.f;
    }
    for (int idx = t; idx < 16 * 384; idx += TPB) {
        int b = idx & 15, k = idx >> 4;
        qf[b][k] = (f16)0.f;
    }

    // x: thread (g,u) loads chan u for M-rows m0=2g, m1=2g+1
    const int m0 = g * 2, m1 = g * 2 + 1;
    const size_t xb0 = ((size_t)(bt * BT + (m0 & 3)) << 16) + ((size_t)u << 10)
                     + ((size_t)(grp * RPB + (m0 >> 2)) << 5);
    const size_t xb1 = ((size_t)(bt * BT + (m1 & 3)) << 16) + ((size_t)u << 10)
                     + ((size_t)(grp * RPB + (m1 >> 2)) << 5);
    // stage x for step 0 (col = -cell: only cell0 valid) into parity-0 slot
    qf[m0][384 + u] = (f16)(((m0 >> 2) == 0) ? x[xb0] : 0.f);
    qf[m1][384 + u] = (f16)(((m1 >> 2) == 0) ? x[xb1] : 0.f);

    for (int s = 0; s < STEPS; ++s) {
        const int par = s & 1;
        const int fhT = par * 64,        nhT = (par ^ 1) * 64;
        const int fhL = 128 + par * 64,  nhL = 128 + (par ^ 1) * 64;
        const int fhD = 256 + par * 64,  nhD = 256 + (par ^ 1) * 64;
        const int fx  = 384 + par * 64,  nx  = 384 + (par ^ 1) * 64;
        const int shT = par * 64,        tnT = (par ^ 1) * 64;
        const int shL = 128 + par * 64,  tnL = 128 + (par ^ 1) * 64;
        const int shD = 256 + par * 64,  tnD = 256 + (par ^ 1) * 64;

        __syncthreads();   // s1 — prev-step tail (rotations, h, x) visible

        // ---- [A] issue poll (waves 0,1 only; own dword; flies over C-pre) ----
        uint32_t wv = 0;
        const uint32_t* sp = hbuf;
        const bool polling = (grp > 0) && (s < LDIM) && (t < 128);
        if (polling) {
            sp = hbuf + (((size_t)((grp - 1) * LDIM + s) * NBT + bt) << 7) + t;
            wv = __hip_atomic_load(sp, __ATOMIC_RELAXED, __HIP_MEMORY_SCOPE_AGENT);
        }
        // x prefetch: per row, next col = s+1-cell
        float nxv0 = 0.f, nxv1 = 0.f;
        {
            const int col0 = s + 1 - (m0 >> 2);
            const int col1 = s + 1 - (m1 >> 2);
            if ((unsigned)col0 < (unsigned)LDIM) nxv0 = x[xb0 + col0];
            if ((unsigned)col1 < (unsigned)LDIM) nxv1 = x[xb1 + col1];
        }

        // ---- [C-pre] GEMM1 k=64:256 (hL, hD, x — all local/rotated) ----
        f32x4 acc[4];
        if (g < 7) {
#pragma unroll
            for (int T = 0; T < 4; ++T)
                acc[T] = (f32x4){bias1[T], bias1[T], bias1[T], bias1[T]};
#pragma unroll
            for (int sc = 2; sc < 8; ++sc) {
                const int base = (sc < 4 ? fhL : sc < 6 ? fhD : fx) + (sc & 1) * 32;
                f16x8 a = *(const f16x8*)&qf[l15][base + lq * 8];
#pragma unroll
                for (int T = 0; T < 4; ++T)
                    acc[T] = __builtin_amdgcn_mfma_f32_16x16x32_f16(a, wreg[T][sc], acc[T], 0, 0, 0);
            }
        }

        // ---- [A'] finish poll; stage cell0 hT (rows 0..3, cur parity) ----
        if (polling) {
            while ((wv & 0x00010001u) != 0x00010001u) {
                __builtin_amdgcn_s_sleep(1);
                wv = __hip_atomic_load(sp, __ATOMIC_RELAXED, __HIP_MEMORY_SCOPE_AGENT);
            }
            const int uu = t >> 1, bp = (t & 1) * 2;
            f16 lo = __builtin_bit_cast(f16, (uint16_t)(wv & 0xFFFFu));
            f16 hi = __builtin_bit_cast(f16, (uint16_t)(wv >> 16));
            qs32[bp][shT + uu]     = (float)lo;  qf[bp][fhT + uu]     = lo;
            qs32[bp + 1][shT + uu] = (float)hi;  qf[bp + 1][fhT + uu] = hi;
        }
        __syncthreads();   // s1b — hT staged visible

        // ---- [C-post] GEMM1 k=0:64 (hT) + sigmoid->rf / z->Gsz ----
        if (g < 7) {
            {
                f16x8 a0 = *(const f16x8*)&qf[l15][fhT + lq * 8];
                f16x8 a1 = *(const f16x8*)&qf[l15][fhT + 32 + lq * 8];
#pragma unroll
                for (int T = 0; T < 4; ++T)
                    acc[T] = __builtin_amdgcn_mfma_f32_16x16x32_f16(a0, wreg[T][0], acc[T], 0, 0, 0);
#pragma unroll
                for (int T = 0; T < 4; ++T)
                    acc[T] = __builtin_amdgcn_mfma_f32_16x16x32_f16(a1, wreg[T][1], acc[T], 0, 0, 0);
            }
            if (g < 3) {
                // g=0: r_l*hL ; g=1: r_t*hT ; g=2: r_d*hD  (cur-parity states)
                const int colbase = (g == 0) ? shL : (g == 1) ? shT : shD;
#pragma unroll
                for (int T = 0; T < 4; ++T)
#pragma unroll
                    for (int r = 0; r < 4; ++r) {
                        float rr = 1.f / (1.f + __expf(-acc[T][r]));
                        int b = lq * 4 + r;
                        rf[b][g * 64 + T * 16 + l15] =
                            (f16)(rr * qs32[b][colbase + T * 16 + l15]);
                    }
            } else {
                const int zb = (g - 3) * 64;
#pragma unroll
                for (int T = 0; T < 4; ++T)
#pragma unroll
                    for (int r = 0; r < 4; ++r)
                        Gsz[lq * 4 + r][zb + T * 16 + l15] = acc[T][r];
            }
        }
        __syncthreads();   // s2 — rf + Gsz ready

        // ---- [E'] waves 4..7: full-K GEMM2 + fused tanh/softmax/combine +
        //      rotations (hL next, hT next for cell+1) + cell3 handoff.
        //      waves 0..3: hD(next) <- hT(cur) rotation. ----
        if (g >= 4) {
            f32x4 aA = (f32x4){0.f, 0.f, 0.f, 0.f};
            f32x4 aB = (f32x4){0.f, 0.f, 0.f, 0.f};
            {
                f16x8 a;
                a = *(const f16x8*)&rf[l15][  0 + lq * 8]; aA = __builtin_amdgcn_mfma_f32_16x16x32_f16(a, wreg2[0], aA, 0, 0, 0);
                a = *(const f16x8*)&rf[l15][ 32 + lq * 8]; aB = __builtin_amdgcn_mfma_f32_16x16x32_f16(a, wreg2[1], aB, 0, 0, 0);
                a = *(const f16x8*)&rf[l15][ 64 + lq * 8]; aA = __builtin_amdgcn_mfma_f32_16x16x32_f16(a, wreg2[2], aA, 0, 0, 0);
                a = *(const f16x8*)&rf[l15][ 96 + lq * 8]; aB = __builtin_amdgcn_mfma_f32_16x16x32_f16(a, wreg2[3], aB, 0, 0, 0);
                a = *(const f16x8*)&rf[l15][128 + lq * 8]; aA = __builtin_amdgcn_mfma_f32_16x16x32_f16(a, wreg2[4], aA, 0, 0, 0);
                a = *(const f16x8*)&rf[l15][160 + lq * 8]; aB = __builtin_amdgcn_mfma_f32_16x16x32_f16(a, wreg2[5], aB, 0, 0, 0);
                a = *(const f16x8*)&qf[l15][fx + lq * 8];      aA = __builtin_amdgcn_mfma_f32_16x16x32_f16(a, wreg2[6], aA, 0, 0, 0);
                a = *(const f16x8*)&qf[l15][fx + 32 + lq * 8]; aB = __builtin_amdgcn_mfma_f32_16x16x32_f16(a, wreg2[7], aB, 0, 0, 0);
            }
            const int n = (g - 4) * 16 + l15;
            uint32_t h16[4];
#pragma unroll
            for (int rr = 0; rr < 4; ++rr) {
                const int b = lq * 4 + rr;
                const int c = b >> 2;
                const int col = s - c;
                const bool valid = (unsigned)col < (unsigned)LDIM;
                float hh = bijE + aA[rr] + aB[rr];
                float e2 = __expf(2.f * hh);
                float th = 1.f - 2.f / (e2 + 1.f);          // tanh
                float zi = Gsz[b][n],        zl = Gsz[b][64 + n];
                float zt = Gsz[b][128 + n],  zd = Gsz[b][192 + n];
                float hT = qs32[b][shT + n], hL = qs32[b][shL + n], hD = qs32[b][shD + n];
                float mx = fmaxf(fmaxf(zi, zl), fmaxf(zt, zd));
                float ei = __expf(zi - mx), el = __expf(zl - mx);
                float et = __expf(zt - mx), ed = __expf(zd - mx);
                float inv = 1.f / (ei + el + et + ed);
                float h  = (el * hL + et * hT + ed * hD + ei * th) * inv;
                float hs = valid ? h : 0.f;                 // gate edge cells
                f16 hf = (f16)hs;
                h16[rr] = (uint32_t)(__builtin_bit_cast(uint16_t, hf) | 1u);
                qs32[b][tnL + n] = hs;                      // hL(next) <- h
                qf[b][nhL + n]   = hf;
                if (b < 12) {                               // hT(next, cell+1)
                    qs32[b + 4][tnT + n] = hs;
                    qf[b + 4][nhT + n]   = hf;
                }
                if (b >= 12 && grp == GRPS - 1 && col == LDIM - 1)
                    out[(size_t)(bt * BT + (b & 3)) * UNITS + n] = h;
            }
            // cell3 handoff: lanes lq==3 hold rows 12..15 -> 2 packed dwords.
            // ATOMIC EXCHANGE (non-returning swap): executes at the MALL
            // coherence point — cannot linger dirty in the producer's XCD L2,
            // unlike a relaxed agent store. This is THE change of R13.
            if (lq == 3 && grp < GRPS - 1 && (unsigned)(s - 3) < (unsigned)LDIM) {
                uint32_t* hp = hbuf + (((size_t)(grp * LDIM + (s - 3)) * NBT + bt) << 7);
                (void)__hip_atomic_exchange(hp + n * 2,     h16[0] | (h16[1] << 16),
                                            __ATOMIC_RELAXED, __HIP_MEMORY_SCOPE_AGENT);
                (void)__hip_atomic_exchange(hp + n * 2 + 1, h16[2] | (h16[3] << 16),
                                            __ATOMIC_RELAXED, __HIP_MEMORY_SCOPE_AGENT);
            }
        } else {
            // waves 0..3: hD(next) <- hT(cur) for all 16 rows
#pragma unroll
            for (int i = 0; i < 4; ++i) {
                const int b = g + 4 * i;
                qs32[b][tnD + u] = qs32[b][shT + u];
                qf[b][nhD + u]   = qf[b][fhT + u];
            }
        }
        // stage next x (thread-own rows, next parity)
        qf[m0][nx + u] = (f16)nxv0;
        qf[m1][nx + u] = (f16)nxv1;
        // next s1 covers cross-wave visibility of all tail writes
    }
}

extern "C" void kernel_launch(void* const* d_in, const int* in_sizes, int n_in,
                              void* d_out, int out_size, void* d_ws, size_t ws_size,
                              hipStream_t stream) {
    const float* x    = (const float*)d_in[0];
    const float* W    = (const float*)d_in[1];
    const float* Urec = (const float*)d_in[2];
    const float* bias = (const float*)d_in[3];
    const float* Wij  = (const float*)d_in[4];
    float* out = (float*)d_out;

    // hbuf: (7 edges * 32 cols * 16 bt) slots x 128 dwords = 1.83 MB << ws.
    // Harness re-poisons ws with 0xAA each launch; 0xAAAA halfwords fail the
    // per-half LSB validity test.
    uint32_t* hbuf = (uint32_t*)d_ws;

    spatial_gru_kernel<<<GRPS * NBT, TPB, 0, stream>>>(
        x, W, Urec, bias, Wij, out, hbuf);
}

// Round 8
// 291.990 us; speedup vs baseline: 1.0018x; 1.0018x over previous
//
#include <hip/hip_runtime.h>
#include <cstdint>
#include <cstddef>

// ---------------------------------------------------------------------------
// SpatialGRU 32x32, B=64, U=64, C=64. R14 = R13 staircase + ONE change:
// CONSUMER POLLS ARE ATOMIC RMWs (fetch_or 0). Theory: a relaxed agent
// atomic LOAD can be serviced by the consumer XCD's own L2, which holds a
// stale clean copy of the hbuf line; it refreshes only on eviction —
// µs-scale and traffic-dependent. This explains R12's fitted ~17us hop
// (light traffic -> slow eviction), R0's ~4.6us (heavy traffic), R11's null
// (spins were cheap local L2 hits; the wait was eviction), and R13's null
// (producer side was never the stale side). A fetch_or(0) executes AT the
// MALL coherence point and can never read the stale local copy.
// Producer keeps atomicExch (coherent-point store, proven neutral).
//
// R12 recap: 8 row-groups x 16 batch-tiles = 128 blocks, 4 rows/block
// staggered (cell k handles col s-k at step s), cells batch-fused into one
// M=16 GEMM pipeline; hT for cells 1..3 via LDS rotation (parity-buffered);
// only cell3 -> hbuf (128 dw/slot), only cell0 polls (128 threads).
// Serial path: 35 steps + 7 inter-block lags. 3 barriers/step.
// Validity: stored halfwords have LSB|=1; ws poison 0xAA fails the check.
// hbuf: (7 grp-edges, 32 cols, 16 bt) slots x 128 dwords = 1.83 MB.
// ---------------------------------------------------------------------------

#define LDIM   32
#define GRPS   8
#define RPB    4
#define NBT    16
#define BT     4
#define TPB    512
#define UNITS  64
#define STEPS  (LDIM + RPB - 1)   // 35

typedef _Float16 f16;
typedef _Float16 f16x8 __attribute__((ext_vector_type(8)));
typedef float    f32x4 __attribute__((ext_vector_type(4)));

__global__ __launch_bounds__(TPB, 2) void spatial_gru_kernel(
    const float* __restrict__ x,     // (B, C, 32, 32)
    const float* __restrict__ W,     // (256, 448)
    const float* __restrict__ Urec,  // (192, 64)
    const float* __restrict__ bias,  // (512,)
    const float* __restrict__ Wij,   // (64, 64)
    float* __restrict__ out,         // (B, U)
    uint32_t* __restrict__ hbuf)
{
    const int p   = blockIdx.x;
    const int grp = p >> 4;          // row group 0..7 (rows grp*4 .. grp*4+3)
    const int bt  = p & 15;          // batch tile 0..15 (batches bt*4..bt*4+3)
    const int t   = (int)threadIdx.x;
    const int u   = t & 63;
    const int g   = t >> 6;          // wave 0..7
    const int l15 = t & 15;          // MFMA A-row lane (M-row = cell*4+batch)
    const int lq  = (t & 63) >> 4;   // MFMA k-quad

    // ---- LDS ----
    // M-row m = cell*4 + batch_in_tile. All per-row, parity double-buffered.
    // qf  (f16): [m][ hT0 0 | hT1 64 | hL0 128 | hL1 192 | hD0 256 | hD1 320
    //               | x0 384 | x1 448 ]
    // qs32(f32): [m][ hT0 0 | hT1 64 | hL0 128 | hL1 192 | hD0 256 | hD1 320 ]
    // rf  (f16): [m][0:192] = r*{hL,hT,hD} (cur step, no parity needed)
    // Gsz (f32): [m][0:256] z logits
    __shared__ __attribute__((aligned(16))) f16 qf[16][520];
    __shared__ __attribute__((aligned(16))) f16 rf[16][200];
    __shared__ float qs32[16][388];
    __shared__ float Gsz [16][260];

    // ---- GEMM1 weights resident (waves 0..6: 64 n-cols each) ----
    f16x8 wreg[4][8];
    float bias1[4] = {0.f, 0.f, 0.f, 0.f};
    if (g < 7) {
        const int nb = g * 64 + l15;
#pragma unroll
        for (int T = 0; T < 4; ++T) {
            bias1[T] = bias[nb + 16 * T];
#pragma unroll
            for (int s = 0; s < 8; ++s) {
                f16x8 v;
#pragma unroll
                for (int jj = 0; jj < 8; ++jj) {
                    int kk = s * 32 + lq * 8 + jj;
                    v[jj] = (f16)W[(size_t)kk * 448 + nb + 16 * T];
                }
                wreg[T][s] = v;
            }
        }
    }
    // ---- GEMM2 weights: waves 4..7 hold FULL K=256 for 16 n-cols each ----
    f16x8 wreg2[8];
    float bijE = 0.f;
    if (g >= 4) {
        const int nn = (g - 4) * 16 + l15;
        bijE = bias[448 + nn];
#pragma unroll
        for (int s = 0; s < 8; ++s) {
            f16x8 v;
#pragma unroll
            for (int jj = 0; jj < 8; ++jj) {
                int kk = s * 32 + lq * 8 + jj;
                float wv = (kk < 192) ? Urec[kk * 64 + nn] : Wij[(kk - 192) * 64 + nn];
                v[jj] = (f16)wv;
            }
            wreg2[s] = v;
        }
    }

    // ---- zero init all states (both parities) ----
    for (int idx = t; idx < 16 * 388; idx += TPB) {
        int b = idx & 15, k = idx >> 4;
        qs32[b][k] = 0.f;
    }
    for (int idx = t; idx < 16 * 384; idx += TPB) {
        int b = idx & 15, k = idx >> 4;
        qf[b][k] = (f16)0.f;
    }

    // x: thread (g,u) loads chan u for M-rows m0=2g, m1=2g+1
    const int m0 = g * 2, m1 = g * 2 + 1;
    const size_t xb0 = ((size_t)(bt * BT + (m0 & 3)) << 16) + ((size_t)u << 10)
                     + ((size_t)(grp * RPB + (m0 >> 2)) << 5);
    const size_t xb1 = ((size_t)(bt * BT + (m1 & 3)) << 16) + ((size_t)u << 10)
                     + ((size_t)(grp * RPB + (m1 >> 2)) << 5);
    // stage x for step 0 (col = -cell: only cell0 valid) into parity-0 slot
    qf[m0][384 + u] = (f16)(((m0 >> 2) == 0) ? x[xb0] : 0.f);
    qf[m1][384 + u] = (f16)(((m1 >> 2) == 0) ? x[xb1] : 0.f);

    for (int s = 0; s < STEPS; ++s) {
        const int par = s & 1;
        const int fhT = par * 64,        nhT = (par ^ 1) * 64;
        const int fhL = 128 + par * 64,  nhL = 128 + (par ^ 1) * 64;
        const int fhD = 256 + par * 64,  nhD = 256 + (par ^ 1) * 64;
        const int fx  = 384 + par * 64,  nx  = 384 + (par ^ 1) * 64;
        const int shT = par * 64,        tnT = (par ^ 1) * 64;
        const int shL = 128 + par * 64,  tnL = 128 + (par ^ 1) * 64;
        const int shD = 256 + par * 64,  tnD = 256 + (par ^ 1) * 64;

        __syncthreads();   // s1 — prev-step tail (rotations, h, x) visible

        // ---- [A] issue poll (waves 0,1 only; own dword; flies over C-pre).
        //      RMW poll: fetch_or(0) executes at the MALL coherence point —
        //      cannot be satisfied by a stale local-XCD L2 line. ----
        uint32_t wv = 0;
        uint32_t* sp = hbuf;
        const bool polling = (grp > 0) && (s < LDIM) && (t < 128);
        if (polling) {
            sp = hbuf + (((size_t)((grp - 1) * LDIM + s) * NBT + bt) << 7) + t;
            wv = __hip_atomic_fetch_or(sp, 0u, __ATOMIC_RELAXED, __HIP_MEMORY_SCOPE_AGENT);
        }
        // x prefetch: per row, next col = s+1-cell
        float nxv0 = 0.f, nxv1 = 0.f;
        {
            const int col0 = s + 1 - (m0 >> 2);
            const int col1 = s + 1 - (m1 >> 2);
            if ((unsigned)col0 < (unsigned)LDIM) nxv0 = x[xb0 + col0];
            if ((unsigned)col1 < (unsigned)LDIM) nxv1 = x[xb1 + col1];
        }

        // ---- [C-pre] GEMM1 k=64:256 (hL, hD, x — all local/rotated) ----
        f32x4 acc[4];
        if (g < 7) {
#pragma unroll
            for (int T = 0; T < 4; ++T)
                acc[T] = (f32x4){bias1[T], bias1[T], bias1[T], bias1[T]};
#pragma unroll
            for (int sc = 2; sc < 8; ++sc) {
                const int base = (sc < 4 ? fhL : sc < 6 ? fhD : fx) + (sc & 1) * 32;
                f16x8 a = *(const f16x8*)&qf[l15][base + lq * 8];
#pragma unroll
                for (int T = 0; T < 4; ++T)
                    acc[T] = __builtin_amdgcn_mfma_f32_16x16x32_f16(a, wreg[T][sc], acc[T], 0, 0, 0);
            }
        }

        // ---- [A'] finish poll (RMW spin); stage cell0 hT (rows 0..3) ----
        if (polling) {
            while ((wv & 0x00010001u) != 0x00010001u) {
                __builtin_amdgcn_s_sleep(1);
                wv = __hip_atomic_fetch_or(sp, 0u, __ATOMIC_RELAXED, __HIP_MEMORY_SCOPE_AGENT);
            }
            const int uu = t >> 1, bp = (t & 1) * 2;
            f16 lo = __builtin_bit_cast(f16, (uint16_t)(wv & 0xFFFFu));
            f16 hi = __builtin_bit_cast(f16, (uint16_t)(wv >> 16));
            qs32[bp][shT + uu]     = (float)lo;  qf[bp][fhT + uu]     = lo;
            qs32[bp + 1][shT + uu] = (float)hi;  qf[bp + 1][fhT + uu] = hi;
        }
        __syncthreads();   // s1b — hT staged visible

        // ---- [C-post] GEMM1 k=0:64 (hT) + sigmoid->rf / z->Gsz ----
        if (g < 7) {
            {
                f16x8 a0 = *(const f16x8*)&qf[l15][fhT + lq * 8];
                f16x8 a1 = *(const f16x8*)&qf[l15][fhT + 32 + lq * 8];
#pragma unroll
                for (int T = 0; T < 4; ++T)
                    acc[T] = __builtin_amdgcn_mfma_f32_16x16x32_f16(a0, wreg[T][0], acc[T], 0, 0, 0);
#pragma unroll
                for (int T = 0; T < 4; ++T)
                    acc[T] = __builtin_amdgcn_mfma_f32_16x16x32_f16(a1, wreg[T][1], acc[T], 0, 0, 0);
            }
            if (g < 3) {
                // g=0: r_l*hL ; g=1: r_t*hT ; g=2: r_d*hD  (cur-parity states)
                const int colbase = (g == 0) ? shL : (g == 1) ? shT : shD;
#pragma unroll
                for (int T = 0; T < 4; ++T)
#pragma unroll
                    for (int r = 0; r < 4; ++r) {
                        float rr = 1.f / (1.f + __expf(-acc[T][r]));
                        int b = lq * 4 + r;
                        rf[b][g * 64 + T * 16 + l15] =
                            (f16)(rr * qs32[b][colbase + T * 16 + l15]);
                    }
            } else {
                const int zb = (g - 3) * 64;
#pragma unroll
                for (int T = 0; T < 4; ++T)
#pragma unroll
                    for (int r = 0; r < 4; ++r)
                        Gsz[lq * 4 + r][zb + T * 16 + l15] = acc[T][r];
            }
        }
        __syncthreads();   // s2 — rf + Gsz ready

        // ---- [E'] waves 4..7: full-K GEMM2 + fused tanh/softmax/combine +
        //      rotations (hL next, hT next for cell+1) + cell3 handoff.
        //      waves 0..3: hD(next) <- hT(cur) rotation. ----
        if (g >= 4) {
            f32x4 aA = (f32x4){0.f, 0.f, 0.f, 0.f};
            f32x4 aB = (f32x4){0.f, 0.f, 0.f, 0.f};
            {
                f16x8 a;
                a = *(const f16x8*)&rf[l15][  0 + lq * 8]; aA = __builtin_amdgcn_mfma_f32_16x16x32_f16(a, wreg2[0], aA, 0, 0, 0);
                a = *(const f16x8*)&rf[l15][ 32 + lq * 8]; aB = __builtin_amdgcn_mfma_f32_16x16x32_f16(a, wreg2[1], aB, 0, 0, 0);
                a = *(const f16x8*)&rf[l15][ 64 + lq * 8]; aA = __builtin_amdgcn_mfma_f32_16x16x32_f16(a, wreg2[2], aA, 0, 0, 0);
                a = *(const f16x8*)&rf[l15][ 96 + lq * 8]; aB = __builtin_amdgcn_mfma_f32_16x16x32_f16(a, wreg2[3], aB, 0, 0, 0);
                a = *(const f16x8*)&rf[l15][128 + lq * 8]; aA = __builtin_amdgcn_mfma_f32_16x16x32_f16(a, wreg2[4], aA, 0, 0, 0);
                a = *(const f16x8*)&rf[l15][160 + lq * 8]; aB = __builtin_amdgcn_mfma_f32_16x16x32_f16(a, wreg2[5], aB, 0, 0, 0);
                a = *(const f16x8*)&qf[l15][fx + lq * 8];      aA = __builtin_amdgcn_mfma_f32_16x16x32_f16(a, wreg2[6], aA, 0, 0, 0);
                a = *(const f16x8*)&qf[l15][fx + 32 + lq * 8]; aB = __builtin_amdgcn_mfma_f32_16x16x32_f16(a, wreg2[7], aB, 0, 0, 0);
            }
            const int n = (g - 4) * 16 + l15;
            uint32_t h16[4];
#pragma unroll
            for (int rr = 0; rr < 4; ++rr) {
                const int b = lq * 4 + rr;
                const int c = b >> 2;
                const int col = s - c;
                const bool valid = (unsigned)col < (unsigned)LDIM;
                float hh = bijE + aA[rr] + aB[rr];
                float e2 = __expf(2.f * hh);
                float th = 1.f - 2.f / (e2 + 1.f);          // tanh
                float zi = Gsz[b][n],        zl = Gsz[b][64 + n];
                float zt = Gsz[b][128 + n],  zd = Gsz[b][192 + n];
                float hT = qs32[b][shT + n], hL = qs32[b][shL + n], hD = qs32[b][shD + n];
                float mx = fmaxf(fmaxf(zi, zl), fmaxf(zt, zd));
                float ei = __expf(zi - mx), el = __expf(zl - mx);
                float et = __expf(zt - mx), ed = __expf(zd - mx);
                float inv = 1.f / (ei + el + et + ed);
                float h  = (el * hL + et * hT + ed * hD + ei * th) * inv;
                float hs = valid ? h : 0.f;                 // gate edge cells
                f16 hf = (f16)hs;
                h16[rr] = (uint32_t)(__builtin_bit_cast(uint16_t, hf) | 1u);
                qs32[b][tnL + n] = hs;                      // hL(next) <- h
                qf[b][nhL + n]   = hf;
                if (b < 12) {                               // hT(next, cell+1)
                    qs32[b + 4][tnT + n] = hs;
                    qf[b + 4][nhT + n]   = hf;
                }
                if (b >= 12 && grp == GRPS - 1 && col == LDIM - 1)
                    out[(size_t)(bt * BT + (b & 3)) * UNITS + n] = h;
            }
            // cell3 handoff: lanes lq==3 hold rows 12..15 -> 2 packed dwords.
            // atomicExch: executes at the MALL coherence point (kept from R13).
            if (lq == 3 && grp < GRPS - 1 && (unsigned)(s - 3) < (unsigned)LDIM) {
                uint32_t* hp = hbuf + (((size_t)(grp * LDIM + (s - 3)) * NBT + bt) << 7);
                (void)__hip_atomic_exchange(hp + n * 2,     h16[0] | (h16[1] << 16),
                                            __ATOMIC_RELAXED, __HIP_MEMORY_SCOPE_AGENT);
                (void)__hip_atomic_exchange(hp + n * 2 + 1, h16[2] | (h16[3] << 16),
                                            __ATOMIC_RELAXED, __HIP_MEMORY_SCOPE_AGENT);
            }
        } else {
            // waves 0..3: hD(next) <- hT(cur) for all 16 rows
#pragma unroll
            for (int i = 0; i < 4; ++i) {
                const int b = g + 4 * i;
                qs32[b][tnD + u] = qs32[b][shT + u];
                qf[b][nhD + u]   = qf[b][fhT + u];
            }
        }
        // stage next x (thread-own rows, next parity)
        qf[m0][nx + u] = (f16)nxv0;
        qf[m1][nx + u] = (f16)nxv1;
        // next s1 covers cross-wave visibility of all tail writes
    }
}

extern "C" void kernel_launch(void* const* d_in, const int* in_sizes, int n_in,
                              void* d_out, int out_size, void* d_ws, size_t ws_size,
                              hipStream_t stream) {
    const float* x    = (const float*)d_in[0];
    const float* W    = (const float*)d_in[1];
    const float* Urec = (const float*)d_in[2];
    const float* bias = (const float*)d_in[3];
    const float* Wij  = (const float*)d_in[4];
    float* out = (float*)d_out;

    // hbuf: (7 edges * 32 cols * 16 bt) slots x 128 dwords = 1.83 MB << ws.
    // Harness re-poisons ws with 0xAA each launch; 0xAAAA halfwords fail the
    // per-half LSB validity test.
    uint32_t* hbuf = (uint32_t*)d_ws;

    spatial_gru_kernel<<<GRPS * NBT, TPB, 0, stream>>>(
        x, W, Urec, bias, Wij, out, hbuf);
}

// Round 9
// 281.756 us; speedup vs baseline: 1.0382x; 1.0363x over previous
//
#include <hip/hip_runtime.h>
#include <cstdint>
#include <cstddef>

// ---------------------------------------------------------------------------
// SpatialGRU 32x32, B=64, U=64, C=64. R15 = R13 staircase + ONE change:
// LDS-ONLY BARRIERS. hipcc emits a full `s_waitcnt vmcnt(0) lgkmcnt(0)`
// before every __syncthreads -> the x HBM prefetch (~900cy), the poll loads,
// and the handoff atomicExch round-trip (~700-900cy) are force-drained into
// the serial path at EVERY barrier, 3x per step. Fitted step cost c≈4.2us vs
// ~1.2-1.5us of actual work — and MfmaUtil (3.1% vs 310 MFMA-cycles/step)
// independently confirms the ~10,000-cycle step. All cross-wave deps inside
// a step are LDS-only, so each __syncthreads is replaced by
//   s_waitcnt lgkmcnt(0) ; s_barrier
// (raw builtin + memory-clobbered asm, the HipKittens pattern). VMEM stays
// in flight across barriers; its consumers carry compiler-counted waits.
// If this is null, the drain isn't the mechanism -> pipeline phases next.
//
// R12 recap: 8 row-groups x 16 batch-tiles = 128 blocks, 4 rows/block
// staggered (cell k handles col s-k at step s), cells batch-fused into one
// M=16 GEMM pipeline; hT for cells 1..3 via LDS rotation (parity-buffered);
// only cell3 -> hbuf (atomicExch, 128 dw/slot), only cell0 polls (128 thr).
// Serial path: 35 steps + 7 inter-block lags. 3 (now cheap) barriers/step.
// Validity: stored halfwords have LSB|=1; ws poison 0xAA fails the check.
// hbuf: (7 grp-edges, 32 cols, 16 bt) slots x 128 dwords = 1.83 MB.
// ---------------------------------------------------------------------------

#define LDIM   32
#define GRPS   8
#define RPB    4
#define NBT    16
#define BT     4
#define TPB    512
#define UNITS  64
#define STEPS  (LDIM + RPB - 1)   // 35

// LDS-only barrier: drain ONLY lgkmcnt (LDS) before s_barrier; leave VMEM
// (x prefetch, polls, handoff exch) in flight. Memory clobbers pin memory
// ops on both sides so the compiler can't cache LDS values across it.
#define LBAR()                                                    \
    do {                                                          \
        asm volatile("s_waitcnt lgkmcnt(0)" ::: "memory");        \
        __builtin_amdgcn_s_barrier();                             \
        asm volatile("" ::: "memory");                            \
    } while (0)

typedef _Float16 f16;
typedef _Float16 f16x8 __attribute__((ext_vector_type(8)));
typedef float    f32x4 __attribute__((ext_vector_type(4)));

__global__ __launch_bounds__(TPB, 2) void spatial_gru_kernel(
    const float* __restrict__ x,     // (B, C, 32, 32)
    const float* __restrict__ W,     // (256, 448)
    const float* __restrict__ Urec,  // (192, 64)
    const float* __restrict__ bias,  // (512,)
    const float* __restrict__ Wij,   // (64, 64)
    float* __restrict__ out,         // (B, U)
    uint32_t* __restrict__ hbuf)
{
    const int p   = blockIdx.x;
    const int grp = p >> 4;          // row group 0..7 (rows grp*4 .. grp*4+3)
    const int bt  = p & 15;          // batch tile 0..15 (batches bt*4..bt*4+3)
    const int t   = (int)threadIdx.x;
    const int u   = t & 63;
    const int g   = t >> 6;          // wave 0..7
    const int l15 = t & 15;          // MFMA A-row lane (M-row = cell*4+batch)
    const int lq  = (t & 63) >> 4;   // MFMA k-quad

    // ---- LDS ----
    // M-row m = cell*4 + batch_in_tile. All per-row, parity double-buffered.
    // qf  (f16): [m][ hT0 0 | hT1 64 | hL0 128 | hL1 192 | hD0 256 | hD1 320
    //               | x0 384 | x1 448 ]
    // qs32(f32): [m][ hT0 0 | hT1 64 | hL0 128 | hL1 192 | hD0 256 | hD1 320 ]
    // rf  (f16): [m][0:192] = r*{hL,hT,hD} (cur step, no parity needed)
    // Gsz (f32): [m][0:256] z logits
    __shared__ __attribute__((aligned(16))) f16 qf[16][520];
    __shared__ __attribute__((aligned(16))) f16 rf[16][200];
    __shared__ float qs32[16][388];
    __shared__ float Gsz [16][260];

    // ---- GEMM1 weights resident (waves 0..6: 64 n-cols each) ----
    f16x8 wreg[4][8];
    float bias1[4] = {0.f, 0.f, 0.f, 0.f};
    if (g < 7) {
        const int nb = g * 64 + l15;
#pragma unroll
        for (int T = 0; T < 4; ++T) {
            bias1[T] = bias[nb + 16 * T];
#pragma unroll
            for (int s = 0; s < 8; ++s) {
                f16x8 v;
#pragma unroll
                for (int jj = 0; jj < 8; ++jj) {
                    int kk = s * 32 + lq * 8 + jj;
                    v[jj] = (f16)W[(size_t)kk * 448 + nb + 16 * T];
                }
                wreg[T][s] = v;
            }
        }
    }
    // ---- GEMM2 weights: waves 4..7 hold FULL K=256 for 16 n-cols each ----
    f16x8 wreg2[8];
    float bijE = 0.f;
    if (g >= 4) {
        const int nn = (g - 4) * 16 + l15;
        bijE = bias[448 + nn];
#pragma unroll
        for (int s = 0; s < 8; ++s) {
            f16x8 v;
#pragma unroll
            for (int jj = 0; jj < 8; ++jj) {
                int kk = s * 32 + lq * 8 + jj;
                float wv = (kk < 192) ? Urec[kk * 64 + nn] : Wij[(kk - 192) * 64 + nn];
                v[jj] = (f16)wv;
            }
            wreg2[s] = v;
        }
    }

    // ---- zero init all states (both parities) ----
    for (int idx = t; idx < 16 * 388; idx += TPB) {
        int b = idx & 15, k = idx >> 4;
        qs32[b][k] = 0.f;
    }
    for (int idx = t; idx < 16 * 384; idx += TPB) {
        int b = idx & 15, k = idx >> 4;
        qf[b][k] = (f16)0.f;
    }

    // x: thread (g,u) loads chan u for M-rows m0=2g, m1=2g+1
    const int m0 = g * 2, m1 = g * 2 + 1;
    const size_t xb0 = ((size_t)(bt * BT + (m0 & 3)) << 16) + ((size_t)u << 10)
                     + ((size_t)(grp * RPB + (m0 >> 2)) << 5);
    const size_t xb1 = ((size_t)(bt * BT + (m1 & 3)) << 16) + ((size_t)u << 10)
                     + ((size_t)(grp * RPB + (m1 >> 2)) << 5);
    // stage x for step 0 (col = -cell: only cell0 valid) into parity-0 slot
    qf[m0][384 + u] = (f16)(((m0 >> 2) == 0) ? x[xb0] : 0.f);
    qf[m1][384 + u] = (f16)(((m1 >> 2) == 0) ? x[xb1] : 0.f);

    for (int s = 0; s < STEPS; ++s) {
        const int par = s & 1;
        const int fhT = par * 64,        nhT = (par ^ 1) * 64;
        const int fhL = 128 + par * 64,  nhL = 128 + (par ^ 1) * 64;
        const int fhD = 256 + par * 64,  nhD = 256 + (par ^ 1) * 64;
        const int fx  = 384 + par * 64,  nx  = 384 + (par ^ 1) * 64;
        const int shT = par * 64,        tnT = (par ^ 1) * 64;
        const int shL = 128 + par * 64,  tnL = 128 + (par ^ 1) * 64;
        const int shD = 256 + par * 64,  tnD = 256 + (par ^ 1) * 64;

        LBAR();            // s1 — prev-step LDS tail (rotations, h, x) visible

        // ---- [A] issue poll (waves 0,1 only; own dword; flies over C-pre) ----
        uint32_t wv = 0;
        const uint32_t* sp = hbuf;
        const bool polling = (grp > 0) && (s < LDIM) && (t < 128);
        if (polling) {
            sp = hbuf + (((size_t)((grp - 1) * LDIM + s) * NBT + bt) << 7) + t;
            wv = __hip_atomic_load(sp, __ATOMIC_RELAXED, __HIP_MEMORY_SCOPE_AGENT);
        }
        // x prefetch: per row, next col = s+1-cell (in flight until step end)
        float nxv0 = 0.f, nxv1 = 0.f;
        {
            const int col0 = s + 1 - (m0 >> 2);
            const int col1 = s + 1 - (m1 >> 2);
            if ((unsigned)col0 < (unsigned)LDIM) nxv0 = x[xb0 + col0];
            if ((unsigned)col1 < (unsigned)LDIM) nxv1 = x[xb1 + col1];
        }

        // ---- [C-pre] GEMM1 k=64:256 (hL, hD, x — all local/rotated) ----
        f32x4 acc[4];
        if (g < 7) {
#pragma unroll
            for (int T = 0; T < 4; ++T)
                acc[T] = (f32x4){bias1[T], bias1[T], bias1[T], bias1[T]};
#pragma unroll
            for (int sc = 2; sc < 8; ++sc) {
                const int base = (sc < 4 ? fhL : sc < 6 ? fhD : fx) + (sc & 1) * 32;
                f16x8 a = *(const f16x8*)&qf[l15][base + lq * 8];
#pragma unroll
                for (int T = 0; T < 4; ++T)
                    acc[T] = __builtin_amdgcn_mfma_f32_16x16x32_f16(a, wreg[T][sc], acc[T], 0, 0, 0);
            }
        }

        // ---- [A'] finish poll; stage cell0 hT (rows 0..3, cur parity) ----
        if (polling) {
            while ((wv & 0x00010001u) != 0x00010001u) {
                __builtin_amdgcn_s_sleep(1);
                wv = __hip_atomic_load(sp, __ATOMIC_RELAXED, __HIP_MEMORY_SCOPE_AGENT);
            }
            const int uu = t >> 1, bp = (t & 1) * 2;
            f16 lo = __builtin_bit_cast(f16, (uint16_t)(wv & 0xFFFFu));
            f16 hi = __builtin_bit_cast(f16, (uint16_t)(wv >> 16));
            qs32[bp][shT + uu]     = (float)lo;  qf[bp][fhT + uu]     = lo;
            qs32[bp + 1][shT + uu] = (float)hi;  qf[bp + 1][fhT + uu] = hi;
        }
        LBAR();            // s1b — hT staged visible (LDS only)

        // ---- [C-post] GEMM1 k=0:64 (hT) + sigmoid->rf / z->Gsz ----
        if (g < 7) {
            {
                f16x8 a0 = *(const f16x8*)&qf[l15][fhT + lq * 8];
                f16x8 a1 = *(const f16x8*)&qf[l15][fhT + 32 + lq * 8];
#pragma unroll
                for (int T = 0; T < 4; ++T)
                    acc[T] = __builtin_amdgcn_mfma_f32_16x16x32_f16(a0, wreg[T][0], acc[T], 0, 0, 0);
#pragma unroll
                for (int T = 0; T < 4; ++T)
                    acc[T] = __builtin_amdgcn_mfma_f32_16x16x32_f16(a1, wreg[T][1], acc[T], 0, 0, 0);
            }
            if (g < 3) {
                // g=0: r_l*hL ; g=1: r_t*hT ; g=2: r_d*hD  (cur-parity states)
                const int colbase = (g == 0) ? shL : (g == 1) ? shT : shD;
#pragma unroll
                for (int T = 0; T < 4; ++T)
#pragma unroll
                    for (int r = 0; r < 4; ++r) {
                        float rr = 1.f / (1.f + __expf(-acc[T][r]));
                        int b = lq * 4 + r;
                        rf[b][g * 64 + T * 16 + l15] =
                            (f16)(rr * qs32[b][colbase + T * 16 + l15]);
                    }
            } else {
                const int zb = (g - 3) * 64;
#pragma unroll
                for (int T = 0; T < 4; ++T)
#pragma unroll
                    for (int r = 0; r < 4; ++r)
                        Gsz[lq * 4 + r][zb + T * 16 + l15] = acc[T][r];
            }
        }
        LBAR();            // s2 — rf + Gsz ready (LDS only)

        // ---- [E'] waves 4..7: full-K GEMM2 + fused tanh/softmax/combine +
        //      rotations (hL next, hT next for cell+1) + cell3 handoff.
        //      waves 0..3: hD(next) <- hT(cur) rotation. ----
        if (g >= 4) {
            f32x4 aA = (f32x4){0.f, 0.f, 0.f, 0.f};
            f32x4 aB = (f32x4){0.f, 0.f, 0.f, 0.f};
            {
                f16x8 a;
                a = *(const f16x8*)&rf[l15][  0 + lq * 8]; aA = __builtin_amdgcn_mfma_f32_16x16x32_f16(a, wreg2[0], aA, 0, 0, 0);
                a = *(const f16x8*)&rf[l15][ 32 + lq * 8]; aB = __builtin_amdgcn_mfma_f32_16x16x32_f16(a, wreg2[1], aB, 0, 0, 0);
                a = *(const f16x8*)&rf[l15][ 64 + lq * 8]; aA = __builtin_amdgcn_mfma_f32_16x16x32_f16(a, wreg2[2], aA, 0, 0, 0);
                a = *(const f16x8*)&rf[l15][ 96 + lq * 8]; aB = __builtin_amdgcn_mfma_f32_16x16x32_f16(a, wreg2[3], aB, 0, 0, 0);
                a = *(const f16x8*)&rf[l15][128 + lq * 8]; aA = __builtin_amdgcn_mfma_f32_16x16x32_f16(a, wreg2[4], aA, 0, 0, 0);
                a = *(const f16x8*)&rf[l15][160 + lq * 8]; aB = __builtin_amdgcn_mfma_f32_16x16x32_f16(a, wreg2[5], aB, 0, 0, 0);
                a = *(const f16x8*)&qf[l15][fx + lq * 8];      aA = __builtin_amdgcn_mfma_f32_16x16x32_f16(a, wreg2[6], aA, 0, 0, 0);
                a = *(const f16x8*)&qf[l15][fx + 32 + lq * 8]; aB = __builtin_amdgcn_mfma_f32_16x16x32_f16(a, wreg2[7], aB, 0, 0, 0);
            }
            const int n = (g - 4) * 16 + l15;
            uint32_t h16[4];
#pragma unroll
            for (int rr = 0; rr < 4; ++rr) {
                const int b = lq * 4 + rr;
                const int c = b >> 2;
                const int col = s - c;
                const bool valid = (unsigned)col < (unsigned)LDIM;
                float hh = bijE + aA[rr] + aB[rr];
                float e2 = __expf(2.f * hh);
                float th = 1.f - 2.f / (e2 + 1.f);          // tanh
                float zi = Gsz[b][n],        zl = Gsz[b][64 + n];
                float zt = Gsz[b][128 + n],  zd = Gsz[b][192 + n];
                float hT = qs32[b][shT + n], hL = qs32[b][shL + n], hD = qs32[b][shD + n];
                float mx = fmaxf(fmaxf(zi, zl), fmaxf(zt, zd));
                float ei = __expf(zi - mx), el = __expf(zl - mx);
                float et = __expf(zt - mx), ed = __expf(zd - mx);
                float inv = 1.f / (ei + el + et + ed);
                float h  = (el * hL + et * hT + ed * hD + ei * th) * inv;
                float hs = valid ? h : 0.f;                 // gate edge cells
                f16 hf = (f16)hs;
                h16[rr] = (uint32_t)(__builtin_bit_cast(uint16_t, hf) | 1u);
                qs32[b][tnL + n] = hs;                      // hL(next) <- h
                qf[b][nhL + n]   = hf;
                if (b < 12) {                               // hT(next, cell+1)
                    qs32[b + 4][tnT + n] = hs;
                    qf[b + 4][nhT + n]   = hf;
                }
                if (b >= 12 && grp == GRPS - 1 && col == LDIM - 1)
                    out[(size_t)(bt * BT + (b & 3)) * UNITS + n] = h;
            }
            // cell3 handoff: lanes lq==3 hold rows 12..15 -> 2 packed dwords.
            // atomicExch at the coherence point; fire-and-forget (stays in
            // flight across the next LBAR — no vmcnt drain).
            if (lq == 3 && grp < GRPS - 1 && (unsigned)(s - 3) < (unsigned)LDIM) {
                uint32_t* hp = hbuf + (((size_t)(grp * LDIM + (s - 3)) * NBT + bt) << 7);
                (void)__hip_atomic_exchange(hp + n * 2,     h16[0] | (h16[1] << 16),
                                            __ATOMIC_RELAXED, __HIP_MEMORY_SCOPE_AGENT);
                (void)__hip_atomic_exchange(hp + n * 2 + 1, h16[2] | (h16[3] << 16),
                                            __ATOMIC_RELAXED, __HIP_MEMORY_SCOPE_AGENT);
            }
        } else {
            // waves 0..3: hD(next) <- hT(cur) for all 16 rows
#pragma unroll
            for (int i = 0; i < 4; ++i) {
                const int b = g + 4 * i;
                qs32[b][tnD + u] = qs32[b][shT + u];
                qf[b][nhD + u]   = qf[b][fhT + u];
            }
        }
        // stage next x (thread-own rows, next parity)
        qf[m0][nx + u] = (f16)nxv0;
        qf[m1][nx + u] = (f16)nxv1;
        // next s1 (LBAR) covers cross-wave visibility of all LDS tail writes
    }
}

extern "C" void kernel_launch(void* const* d_in, const int* in_sizes, int n_in,
                              void* d_out, int out_size, void* d_ws, size_t ws_size,
                              hipStream_t stream) {
    const float* x    = (const float*)d_in[0];
    const float* W    = (const float*)d_in[1];
    const float* Urec = (const float*)d_in[2];
    const float* bias = (const float*)d_in[3];
    const float* Wij  = (const float*)d_in[4];
    float* out = (float*)d_out;

    // hbuf: (7 edges * 32 cols * 16 bt) slots x 128 dwords = 1.83 MB << ws.
    // Harness re-poisons ws with 0xAA each launch; 0xAAAA halfwords fail the
    // per-half LSB validity test.
    uint32_t* hbuf = (uint32_t*)d_ws;

    spatial_gru_kernel<<<GRPS * NBT, TPB, 0, stream>>>(
        x, W, Urec, bias, Wij, out, hbuf);
}